// Round 2
// baseline (176.774 us; speedup 1.0000x reference)
//
#include <hip/hip_runtime.h>
#include <math.h>

#define R_ROUTES 1152
#define N_CAPS 10
#define C_IN 8
#define D_DIM 16
#define B_BATCH 128
#define JD 160                      // N_CAPS * D_DIM
#define KK 9216                     // R_ROUTES * C_IN (GEMM K)
#define KSPLIT 48                   // 24 routes = 192 k per split
#define RS 24                       // routes per k-split
#define NG 5                        // jd groups of 32
#define BH 2                        // batch halves (occupancy split)
#define NBLK (KSPLIT * NG * BH)     // 480 blocks per iter dispatch

typedef __attribute__((ext_vector_type(8))) short short8;   // 8 bf16 (4 VGPRs)
typedef __attribute__((ext_vector_type(4))) float f32x4;    // MFMA accumulator

__device__ inline unsigned short f2bf(float f) {            // RNE fp32 -> bf16
    unsigned int u = __float_as_uint(f);
    unsigned int r = u + 0x7FFFu + ((u >> 16) & 1u);
    return (unsigned short)(r >> 16);
}
__device__ inline float bf2f(unsigned short h) {
    return __uint_as_float(((unsigned int)h) << 16);
}

// ---------------------------------------------------------------------------
// ws layout (byte offsets):
//   b_ij fp32 [1152][10]       @ 0         (46080 B)
//   s0/s1/s2 fp32 [128][160]   @ 46080     (3 x 81920 B)
//   cnt  u32[3]                @ 291840    (last-block counters, zeroed by prep)
//   xh   bf16 [128][9216]      @ 292096    A-layout [b][k]
//   xl   bf16 [128][9216]      @ 2651392
//   xT   bf16 [9216][128]      @ 5010688   A-layout for M2 ([rc][b])
//   vT   bf16 [160][128]       = d_out reused as scratch (40KB < 80KB out)
// Lesson log:
//  R5/R6: in-kernel grid barriers ~20us each -> multi-dispatch.
//  R7/R9 (112.4us): atomic split-K KSPLIT=48 + fused squash/agree.
//  R10/R11: atomic throughput exonerated. R12: batch-split grid (48,5,2).
//  R13 REGRESSED (150us): per-block redundant 24-route agreement (10x MFMA,
//    30 serial {4-dep-MFMA + scattered W float4 + 5-dep shfl} iters) at
//    2 blk/CU (58KB LDS) = 55us/dispatch, MfmaUtil 2.8%. Redundant AGREEMENT
//    is latency-poison; redundant SQUASH was the only cheap part.
//    Validated: last-block counter (vmcnt drain + threadfence + agent loads).
//  R14 (this): round-0 structure, 7 -> 6 dispatches, no redundant agreement.
//    - squash folded into k_iter's last block -> vT global (out as scratch);
//      k_ag reads B-fragments from L2-hot vT (no vb LDS, no per-block squash,
//      no bank conflicts). k_rs_final folded into iter3's last block.
// ---------------------------------------------------------------------------

// prep: x -> bf16 hi/lo + transpose; zero b_ij, s0..s2, cnt[3]
__global__ __launch_bounds__(256) void k_prep(
    const float* __restrict__ x, unsigned short* __restrict__ xh,
    unsigned short* __restrict__ xl, unsigned short* __restrict__ xT,
    float* __restrict__ b_ij, float* __restrict__ s_all,
    unsigned int* __restrict__ cnt) {
    __shared__ float tile[32][33];
    int bx = blockIdx.x;            // rc tile 0..287
    int by = blockIdx.y;            // b tile 0..3
    int t = threadIdx.x;
    int tx = t & 31, ty = t >> 5;
#pragma unroll
    for (int i = 0; i < 4; i++) {
        int row = ty + i * 8;       // b_local
        size_t idx = (size_t)(by * 32 + row) * KK + bx * 32 + tx;
        float v = x[idx];
        tile[row][tx] = v;
        unsigned short hi = f2bf(v);
        xh[idx] = hi;
        xl[idx] = f2bf(v - bf2f(hi));
    }
    __syncthreads();
#pragma unroll
    for (int i = 0; i < 4; i++) {
        int row = ty + i * 8;       // rc_local
        xT[(size_t)(bx * 32 + row) * B_BATCH + by * 32 + tx] = f2bf(tile[tx][row]);
    }
    int bid = by * 288 + bx;        // 0..1151
    if (bid < 240) s_all[bid * 256 + t] = 0.f;              // 240*256 == 3*20480
    else if (bid < 285) b_ij[(bid - 240) * 256 + t] = 0.f;  // 45*256 == 11520
    else if (bid == 285 && t < 3) cnt[t] = 0u;
}

// GEMM iteration: softmax(b_ij) -> c (or c=0.1 if FIRST), stage c*W-hi bf16
// in LDS, MFMA (ah*bh + al*bh) over 192-k x 32-jd x 64-b, atomicAdd into s.
// Grid (48, 5, 2), block 256. Last finishing block (counter):
//   SQ==1: squash(s) -> vT bf16 [jd][b]   (for the following k_ag)
//   SQ==2: squash(s) -> out fp32 [b][jd]  (final result)
template <int FIRST, int SQ>
__global__ __launch_bounds__(256) void k_iter(
    const unsigned short* __restrict__ xh, const unsigned short* __restrict__ xl,
    const float* __restrict__ W, const float* __restrict__ b_ij,
    float* __restrict__ s, unsigned int* __restrict__ cnt,
    unsigned short* __restrict__ vT, float* __restrict__ out) {
    __shared__ float cs[RS][N_CAPS];
    __shared__ unsigned short bhs[32][200];   // [jd_l][k_l], 400B rows (16B mult)
    __shared__ unsigned int lastflag;
    int t = threadIdx.x;
    int ks = blockIdx.x, ng = blockIdx.y, bh = blockIdx.z;
    int r0 = ks * RS, jd0 = ng * 32, b_base = bh * 64;

    if (!FIRST && t < RS) {          // softmax for this block's routes
        float bj[N_CAPS], m = -1e30f;
#pragma unroll
        for (int j = 0; j < N_CAPS; j++) { bj[j] = b_ij[(r0 + t) * N_CAPS + j]; m = fmaxf(m, bj[j]); }
        float sum = 0.f;
#pragma unroll
        for (int j = 0; j < N_CAPS; j++) { bj[j] = expf(bj[j] - m); sum += bj[j]; }
        float inv = 1.f / sum;
#pragma unroll
        for (int j = 0; j < N_CAPS; j++) cs[t][j] = bj[j] * inv;
    }
    __syncthreads();

    // stage 24 routes x 32 jd of c*W hi: 768 pairs, 8 fp32 each
#pragma unroll
    for (int p = t; p < RS * 32; p += 256) {
        int rl = p >> 5, jdl = p & 31;
        const float* wp = W + ((size_t)(r0 + rl) * JD + jd0 + jdl) * C_IN;
        float c = FIRST ? 0.1f : cs[rl][(jd0 + jdl) >> 4];
        short8 vh;
#pragma unroll
        for (int i = 0; i < 8; i++) vh[i] = (short)f2bf(wp[i] * c);
        *(short8*)&bhs[jdl][rl * 8] = vh;    // k_local = rl*8+i
    }
    __syncthreads();

    int w = t >> 6, l = t & 63, row = l & 15, quad = l >> 4;
    // wave w owns m-tile w: batch rows b_base + w*16 .. +16
    const short8* pah = (const short8*)(xh + (size_t)(b_base + w * 16 + row) * KK + ks * 192);
    const short8* pal = (const short8*)(xl + (size_t)(b_base + w * 16 + row) * KK + ks * 192);
    f32x4 acc0 = {0,0,0,0}, acc1 = {0,0,0,0};
#pragma unroll
    for (int st = 0; st < 6; st++) {         // K = 192 = 6 steps of 32
        short8 Bh0 = *(const short8*)&bhs[row][st * 32 + quad * 8];
        short8 Bh1 = *(const short8*)&bhs[16 + row][st * 32 + quad * 8];
        short8 Ah = pah[st * 4 + quad], Al = pal[st * 4 + quad];
        acc0 = __builtin_amdgcn_mfma_f32_16x16x32_bf16(Ah, Bh0, acc0, 0, 0, 0);
        acc0 = __builtin_amdgcn_mfma_f32_16x16x32_bf16(Al, Bh0, acc0, 0, 0, 0);
        acc1 = __builtin_amdgcn_mfma_f32_16x16x32_bf16(Ah, Bh1, acc1, 0, 0, 0);
        acc1 = __builtin_amdgcn_mfma_f32_16x16x32_bf16(Al, Bh1, acc1, 0, 0, 0);
    }
#pragma unroll
    for (int i = 0; i < 4; i++) {            // C/D: col=lane&15 (jd), row=quad*4+i (b)
        int b0 = b_base + w * 16 + quad * 4 + i;
        atomicAdd(&s[(size_t)b0 * JD + jd0 + row],      acc0[i]);
        atomicAdd(&s[(size_t)b0 * JD + jd0 + 16 + row], acc1[i]);
    }

    // --- last finishing block: squash(s) -> vT or out -------------------
    __syncthreads();                 // drains this block's atomics (vmcnt 0)
    if (t == 0) {
        __threadfence();             // release to agent scope
        unsigned int old = atomicAdd(cnt, 1u);
        lastflag = (old == (unsigned)(NBLK - 1)) ? 1u : 0u;
    }
    __syncthreads();
    if (lastflag) {
        __threadfence();             // acquire side
#pragma unroll
        for (int q = 0; q < 5; q++) {
            int pi = t * 5 + q;      // (b, j) pair, 1280 total
            int b = pi / N_CAPS, j = pi % N_CAPS;
            float* sp = s + (size_t)b * JD + j * D_DIM;
            float sv[D_DIM], sqn = 0.f;
#pragma unroll
            for (int d = 0; d < D_DIM; d++) {
                sv[d] = __hip_atomic_load(sp + d, __ATOMIC_RELAXED, __HIP_MEMORY_SCOPE_AGENT);
                sqn = fmaf(sv[d], sv[d], sqn);
            }
            float scale = sqn / ((1.f + sqn) * sqrtf(sqn));
            if (SQ == 1) {
#pragma unroll
                for (int d = 0; d < D_DIM; d++)
                    vT[(size_t)(j * D_DIM + d) * B_BATCH + b] = f2bf(sv[d] * scale);
            } else {
#pragma unroll
                for (int d = 0; d < D_DIM; d++)
                    out[(size_t)b * JD + j * D_DIM + d] = sv[d] * scale;
            }
        }
    }
}

// Agreement: M2[rc,jd] = sum_b xT[rc,b]*v[b,jd] via MFMA (B-fragments straight
// from L2-hot vT global, no LDS staging), then contract with W over c and
// update b_ij. Block owns 4 routes (32 rc rows). Grid 288.
__global__ __launch_bounds__(256) void k_ag(
    const unsigned short* __restrict__ xT, const unsigned short* __restrict__ vT,
    const float* __restrict__ W, float* __restrict__ b_ij) {
    __shared__ float m2[32][164];            // [rc_local][jd], +4 pad
    int t = threadIdx.x;
    int r0 = blockIdx.x * 4, rc0 = blockIdx.x * 32;

    int w = t >> 6, l = t & 63, row = l & 15, quad = l >> 4;
    for (int u = w; u < 20; u += 4) {        // 2 m-tiles x 10 n-tiles
        int mt = u / 10, nt = u % 10;
        const short8* pa = (const short8*)(xT + (size_t)(rc0 + mt * 16 + row) * B_BATCH);
        const short8* pb = (const short8*)(vT + (size_t)(nt * D_DIM + row) * B_BATCH);
        f32x4 acc = {0,0,0,0};
#pragma unroll
        for (int st = 0; st < 4; st++)       // K = 128 = 4 steps of 32
            acc = __builtin_amdgcn_mfma_f32_16x16x32_bf16(pa[st * 4 + quad], pb[st * 4 + quad], acc, 0, 0, 0);
#pragma unroll
        for (int i = 0; i < 4; i++)          // C/D: col=jd, row=rc_local
            m2[mt * 16 + quad * 4 + i][nt * 16 + row] = acc[i];
    }
    __syncthreads();

    for (int p = t; p < 640; p += 256) {     // 4 routes x 160 jd
        int rl = p / JD, jd = p % JD;
        const float* wp = W + ((size_t)(r0 + rl) * JD + jd) * C_IN;
        float a = 0.f;
#pragma unroll
        for (int c = 0; c < C_IN; c++)
            a = fmaf(wp[c], m2[rl * 8 + c][jd], a);
#pragma unroll
        for (int off = 1; off < 16; off <<= 1) a += __shfl_xor(a, off, 16);
        if ((jd & 15) == 0)
            b_ij[(r0 + rl) * N_CAPS + (jd >> 4)] += a * (1.f / B_BATCH);
    }
}

extern "C" void kernel_launch(void* const* d_in, const int* in_sizes, int n_in,
                              void* d_out, int out_size, void* d_ws, size_t ws_size,
                              hipStream_t stream) {
    const float* x = (const float*)d_in[0];   // [128,1152,8]
    const float* W = (const float*)d_in[1];   // [1,1152,10,16,8]
    float* out = (float*)d_out;               // [128,10,16,1]
    char* ws = (char*)d_ws;

    float*          b_ij = (float*)(ws + 0);
    float*          s0   = (float*)(ws + 46080);
    float*          s1   = (float*)(ws + 46080 + 81920);
    float*          s2   = (float*)(ws + 46080 + 163840);
    unsigned int*   cnt  = (unsigned int*)(ws + 291840);
    unsigned short* xh   = (unsigned short*)(ws + 292096);
    unsigned short* xl   = (unsigned short*)(ws + 2651392);
    unsigned short* xT   = (unsigned short*)(ws + 5010688);
    unsigned short* vT   = (unsigned short*)d_out;  // 40KB scratch inside out
                                                    // (rewritten by final tail)

    k_prep<<<dim3(288, 4), 256, 0, stream>>>(x, xh, xl, xT, b_ij, s0, cnt);

    // iter1 (c=0.1) -> s0; last block: squash(s0) -> vT
    k_iter<1, 1><<<dim3(KSPLIT, NG, BH), 256, 0, stream>>>(
        xh, xl, W, b_ij, s0, cnt + 0, vT, out);
    // agreement 1: b_ij += mean_b <u_hat, v>
    k_ag<<<288, 256, 0, stream>>>(xT, vT, W, b_ij);

    // iter2 -> s1; last block: squash(s1) -> vT
    k_iter<0, 1><<<dim3(KSPLIT, NG, BH), 256, 0, stream>>>(
        xh, xl, W, b_ij, s1, cnt + 1, vT, out);
    // agreement 2
    k_ag<<<288, 256, 0, stream>>>(xT, vT, W, b_ij);

    // iter3 -> s2; last block: final squash(s2) -> out
    k_iter<0, 2><<<dim3(KSPLIT, NG, BH), 256, 0, stream>>>(
        xh, xl, W, b_ij, s2, cnt + 2, vT, out);
}

// Round 3
// 148.001 us; speedup vs baseline: 1.1944x; 1.1944x over previous
//
#include <hip/hip_runtime.h>
#include <math.h>

#define R_ROUTES 1152
#define N_CAPS 10
#define C_IN 8
#define D_DIM 16
#define B_BATCH 128
#define JD 160                      // N_CAPS * D_DIM
#define KK 9216                     // R_ROUTES * C_IN (GEMM K)
#define KSPLIT 48                   // 24 routes = 192 k per split
#define RS 24                       // routes per k-split
#define NG 5                        // jd groups of 32
#define BH 2                        // batch halves
#define NBLK (KSPLIT * NG * BH)     // 480 blocks per iter grid
#define NSIB 10                     // siblings per route-chunk (NG*BH)

typedef __attribute__((ext_vector_type(8))) short short8;   // 8 bf16 (4 VGPRs)
typedef __attribute__((ext_vector_type(4))) float f32x4;    // MFMA accumulator

__device__ inline unsigned short f2bf(float f) {            // RNE fp32 -> bf16
    unsigned int u = __float_as_uint(f);
    unsigned int r = u + 0x7FFFu + ((u >> 16) & 1u);
    return (unsigned short)(r >> 16);
}
__device__ inline float bf2f(unsigned short h) {
    return __uint_as_float(((unsigned int)h) << 16);
}

// ---------------------------------------------------------------------------
// ws layout (byte offsets):
//   b_ij   fp32 [1152][10]     @ 0         (46080)   running logits (plain)
//   s0/s1/s2 fp32 [128][160]   @ 46080     (3x81920 -> ends 291840)
//   c1/c2  u32 [48]            @ 291840 / 292032  (chunk barriers; ends 292224)
//   bupd_g fp32 [1152][10]     @ 292224    (46080)   agent-scope b_new exchange
//   xT     bf16 [9216][128]    @ 338304    (2359296) A-layout for M2 ([rc][b])
// Lesson log:
//  R5/R6: GRID-wide in-kernel barriers ~20us each -> avoid.
//  R7/R9 (112.4us): atomic split-K KSPLIT=48, 7 dispatches. R10/R11: atomic
//    throughput exonerated. R12: batch-split grid (48,5,2).
//  R13 REGRESSED (150us): every block redundantly did the FULL 24-route
//    agreement (30 serial tiles/wave) -> 55us/dispatch. Redundant SQUASH was
//    cheap; redundant AGREEMENT was poison.
//  R14 REGRESSED (177us): single-block squash tail = 20480 agent-scope SCALAR
//    atomic loads serially appended to each iter dispatch (~15-25us x3).
//    Lesson: tails must be parallel-wide + plain vectorized loads.
//  R15 (this): R0 structure, 7 -> 5 dispatches, no serial tails:
//    - xh/xl deleted: iter blocks read x fp32 directly, hi/lo split in regs
//      (bit-identical math) -> iter1 independent of prep -> transpose fused
//      into iter1 dispatch as extra blocks.
//    - va+iter merged via 10-block chunk-local barrier: each sibling computes
//      a DISJOINT 12/120 m2-tile slice (3 tiles/wave, k_va-level parallelism),
//      single-writer agent-scope stores of b_new, counter barrier (480 blocks
//      all resident: 57.3KB LDS -> 2 blk/CU -> capacity 512 >= 480), softmax
//      reads 240 agent loads. Squash stays per-block redundant (float4 loads).
// ---------------------------------------------------------------------------

__global__ __launch_bounds__(256) void k_zero(float* __restrict__ p) {
    int i = blockIdx.x * 256 + threadIdx.x;   // 72 blocks: 18432 float4 slots
    if (i < 18264) ((f32x4*)p)[i] = (f32x4){0.f, 0.f, 0.f, 0.f};
}

// Dispatch 1: blocks 0..479 = iter1 (c = 0.1, A from x fp32);
//             blocks 480..767 = transpose x -> xT (4 b-tiles each)
__global__ __launch_bounds__(256) void k_first(
    const float* __restrict__ x, const float* __restrict__ W,
    unsigned short* __restrict__ xT, float* __restrict__ s) {
    __shared__ unsigned short bhs[32][200];   // iter half
    __shared__ float tile[32][33];            // transpose half
    int id = blockIdx.x;
    int t = threadIdx.x;

    if (id >= NBLK) {                         // ---- transpose role ----
        int bx = id - NBLK;                   // rc tile 0..287
        int tx = t & 31, ty = t >> 5;
        for (int by = 0; by < 4; by++) {
            if (by) __syncthreads();
#pragma unroll
            for (int i = 0; i < 4; i++) {
                int row = ty + i * 8;         // b_local
                tile[row][tx] = x[(size_t)(by * 32 + row) * KK + bx * 32 + tx];
            }
            __syncthreads();
#pragma unroll
            for (int i = 0; i < 4; i++) {
                int row = ty + i * 8;         // rc_local
                xT[(size_t)(bx * 32 + row) * B_BATCH + by * 32 + tx] = f2bf(tile[tx][row]);
            }
        }
        return;
    }

    // ---- iter1 role ----
    int ks = id % KSPLIT, ng = (id / KSPLIT) % NG, bh = id / (KSPLIT * NG);
    int r0 = ks * RS, jd0 = ng * 32, b_base = bh * 64;

    // stage 0.1*W hi (bf16): 768 (route,jd) pairs, 8 fp32 each
#pragma unroll
    for (int p = t; p < RS * 32; p += 256) {
        int rl = p >> 5, jdl = p & 31;
        const float* wp = W + ((size_t)(r0 + rl) * JD + jd0 + jdl) * C_IN;
        short8 vh;
#pragma unroll
        for (int i = 0; i < 8; i++) vh[i] = (short)f2bf(wp[i] * 0.1f);
        *(short8*)&bhs[jdl][rl * 8] = vh;
    }
    __syncthreads();

    int w = t >> 6, l = t & 63, row = l & 15, quad = l >> 4;
    const float* px = x + (size_t)(b_base + w * 16 + row) * KK + ks * 192;
    f32x4 acc0 = {0,0,0,0}, acc1 = {0,0,0,0};
#pragma unroll
    for (int st = 0; st < 6; st++) {          // K = 192 = 6 steps of 32
        float4 x0 = *(const float4*)(px + st * 32 + quad * 8);
        float4 x1 = *(const float4*)(px + st * 32 + quad * 8 + 4);
        short8 Ah, Al;
        float xv[8] = {x0.x, x0.y, x0.z, x0.w, x1.x, x1.y, x1.z, x1.w};
#pragma unroll
        for (int i = 0; i < 8; i++) {
            unsigned short h = f2bf(xv[i]);
            Ah[i] = (short)h;
            Al[i] = (short)f2bf(xv[i] - bf2f(h));
        }
        short8 Bh0 = *(const short8*)&bhs[row][st * 32 + quad * 8];
        short8 Bh1 = *(const short8*)&bhs[16 + row][st * 32 + quad * 8];
        acc0 = __builtin_amdgcn_mfma_f32_16x16x32_bf16(Ah, Bh0, acc0, 0, 0, 0);
        acc0 = __builtin_amdgcn_mfma_f32_16x16x32_bf16(Al, Bh0, acc0, 0, 0, 0);
        acc1 = __builtin_amdgcn_mfma_f32_16x16x32_bf16(Ah, Bh1, acc1, 0, 0, 0);
        acc1 = __builtin_amdgcn_mfma_f32_16x16x32_bf16(Al, Bh1, acc1, 0, 0, 0);
    }
#pragma unroll
    for (int i = 0; i < 4; i++) {             // C/D: col=lane&15 (jd), row=quad*4+i (b)
        int b0 = b_base + w * 16 + quad * 4 + i;
        atomicAdd(&s[(size_t)b0 * JD + jd0 + row],      acc0[i]);
        atomicAdd(&s[(size_t)b0 * JD + jd0 + 16 + row], acc1[i]);
    }
}

// Fused routing iteration (va_k + iter_{k+1}):
//   A: squash(s_prev) -> vb LDS (per-block redundant, float4 loads)
//   B: agreement slice: 12 of 120 m2-tiles (disjoint per sibling), in-register
//      W-contract (verified R13 epilogue), b_new = b_ij + upd -> agent store
//      + plain b_ij store (for next dispatch)
//   barrier: 10-sibling counter
//   C: softmax (agent loads of b_new) -> cs
//   D: stage c*W hi    E: main GEMM (A from x fp32) -> atomicAdd s_cur
__global__ __launch_bounds__(256) void k_fused(
    const float* __restrict__ x, const unsigned short* __restrict__ xT,
    const float* __restrict__ W, float* __restrict__ b_ij,
    const float* __restrict__ s_prev, float* __restrict__ s_cur,
    float* __restrict__ bupd_g, unsigned int* __restrict__ ccnt) {
    __shared__ unsigned short vb[JD][136];    // [jd][b], +8 pad (43520 B)
    __shared__ unsigned short bhs[32][200];   // (12800 B)
    __shared__ float cs[RS][N_CAPS];          // (960 B)   total 57280 B
    int t = threadIdx.x;
    int ks = blockIdx.x, ng = blockIdx.y, bh = blockIdx.z;
    int r0 = ks * RS, jd0 = ng * 32, b_base = bh * 64;
    int sib = bh * NG + ng;                   // 0..9

    // --- Phase A: squash(s_prev) -> vb ---------------------------------
#pragma unroll
    for (int q = 0; q < 5; q++) {
        int pi = t * 5 + q;                   // (b, j) pair, 1280 total
        int b = pi / N_CAPS, j = pi % N_CAPS;
        const float4* sp4 = (const float4*)(s_prev + (size_t)b * JD + j * D_DIM);
        float4 a0 = sp4[0], a1 = sp4[1], a2 = sp4[2], a3 = sp4[3];
        float sv[D_DIM] = {a0.x,a0.y,a0.z,a0.w, a1.x,a1.y,a1.z,a1.w,
                           a2.x,a2.y,a2.z,a2.w, a3.x,a3.y,a3.z,a3.w};
        float sqn = 0.f;
#pragma unroll
        for (int d = 0; d < D_DIM; d++) sqn = fmaf(sv[d], sv[d], sqn);
        float scale = sqn / ((1.f + sqn) * sqrtf(sqn));
#pragma unroll
        for (int d = 0; d < D_DIM; d++)
            vb[j * D_DIM + d][b] = f2bf(sv[d] * scale);
    }
    __syncthreads();

    int w = t >> 6, l = t & 63, row = l & 15, quad = l >> 4;
    int rhalf = l >> 5, cbase = (quad & 1) * 4;
    int rc0 = ks * 192;

    // --- Phase B: agreement slice (12 disjoint tiles, 3 per wave) -------
#pragma unroll
    for (int jt = 0; jt < 3; jt++) {
        int tile = sib * 12 + w + jt * 4;     // sib*12 .. sib*12+11
        int mt = tile / 10, nt = tile % 10;
        const short8* pa = (const short8*)(xT + (size_t)(rc0 + mt * 16 + row) * B_BATCH);
        f32x4 acc = {0,0,0,0};
#pragma unroll
        for (int st = 0; st < 4; st++)        // K = 128 = 4 steps of 32
            acc = __builtin_amdgcn_mfma_f32_16x16x32_bf16(
                pa[st * 4 + quad], *(const short8*)&vb[nt * 16 + row][st * 32 + quad * 8],
                acc, 0, 0, 0);
        // in-register W contract (verified R13): acc[i] = M2 at
        // rc = mt*16+quad*4+i (route 2mt+rhalf, c=(quad&1)*4+i), jd = nt*16+row
        int r = r0 + 2 * mt + rhalf;
        const float* wp = W + ((size_t)r * JD + nt * 16 + row) * C_IN + cbase;
        float4 w4 = *(const float4*)wp;
        float part = acc[0]*w4.x + acc[1]*w4.y + acc[2]*w4.z + acc[3]*w4.w;
#pragma unroll
        for (int off = 1; off < 32; off <<= 1) part += __shfl_xor(part, off, 32);
        if ((l & 31) == 0) {                  // single writer per (r, nt)
            float val = b_ij[r * N_CAPS + nt] + part * (1.f / (float)B_BATCH);
            __hip_atomic_store(&bupd_g[r * N_CAPS + nt], val,
                               __ATOMIC_RELAXED, __HIP_MEMORY_SCOPE_AGENT);
            b_ij[r * N_CAPS + nt] = val;      // plain: read by NEXT dispatch only
        }
    }

    // --- chunk-local barrier (10 siblings, all provably resident) -------
    __syncthreads();                          // drain this block's stores
    if (t == 0) {
        __hip_atomic_fetch_add(ccnt + ks, 1u, __ATOMIC_ACQ_REL,
                               __HIP_MEMORY_SCOPE_AGENT);
        while (__hip_atomic_load(ccnt + ks, __ATOMIC_ACQUIRE,
                                 __HIP_MEMORY_SCOPE_AGENT) < (unsigned)NSIB)
            __builtin_amdgcn_s_sleep(2);
    }
    __syncthreads();

    // --- Phase C: softmax over this chunk's 24 routes --------------------
    if (t < RS) {
        float bj[N_CAPS], m = -1e30f;
#pragma unroll
        for (int j = 0; j < N_CAPS; j++) {
            bj[j] = __hip_atomic_load(&bupd_g[(r0 + t) * N_CAPS + j],
                                      __ATOMIC_RELAXED, __HIP_MEMORY_SCOPE_AGENT);
            m = fmaxf(m, bj[j]);
        }
        float sum = 0.f;
#pragma unroll
        for (int j = 0; j < N_CAPS; j++) { bj[j] = expf(bj[j] - m); sum += bj[j]; }
        float inv = 1.f / sum;
#pragma unroll
        for (int j = 0; j < N_CAPS; j++) cs[t][j] = bj[j] * inv;
    }
    __syncthreads();

    // --- Phase D: stage c*W hi -------------------------------------------
#pragma unroll
    for (int p = t; p < RS * 32; p += 256) {
        int rl = p >> 5, jdl = p & 31;
        const float* wp = W + ((size_t)(r0 + rl) * JD + jd0 + jdl) * C_IN;
        float c = cs[rl][(jd0 + jdl) >> 4];
        short8 vh;
#pragma unroll
        for (int i = 0; i < 8; i++) vh[i] = (short)f2bf(wp[i] * c);
        *(short8*)&bhs[jdl][rl * 8] = vh;
    }
    __syncthreads();

    // --- Phase E: main GEMM (A from x fp32, hi/lo split in regs) ---------
    const float* px = x + (size_t)(b_base + w * 16 + row) * KK + ks * 192;
    f32x4 acc0 = {0,0,0,0}, acc1 = {0,0,0,0};
#pragma unroll
    for (int st = 0; st < 6; st++) {
        float4 x0 = *(const float4*)(px + st * 32 + quad * 8);
        float4 x1 = *(const float4*)(px + st * 32 + quad * 8 + 4);
        short8 Ah, Al;
        float xv[8] = {x0.x, x0.y, x0.z, x0.w, x1.x, x1.y, x1.z, x1.w};
#pragma unroll
        for (int i = 0; i < 8; i++) {
            unsigned short h = f2bf(xv[i]);
            Ah[i] = (short)h;
            Al[i] = (short)f2bf(xv[i] - bf2f(h));
        }
        short8 Bh0 = *(const short8*)&bhs[row][st * 32 + quad * 8];
        short8 Bh1 = *(const short8*)&bhs[16 + row][st * 32 + quad * 8];
        acc0 = __builtin_amdgcn_mfma_f32_16x16x32_bf16(Ah, Bh0, acc0, 0, 0, 0);
        acc0 = __builtin_amdgcn_mfma_f32_16x16x32_bf16(Al, Bh0, acc0, 0, 0, 0);
        acc1 = __builtin_amdgcn_mfma_f32_16x16x32_bf16(Ah, Bh1, acc1, 0, 0, 0);
        acc1 = __builtin_amdgcn_mfma_f32_16x16x32_bf16(Al, Bh1, acc1, 0, 0, 0);
    }
#pragma unroll
    for (int i = 0; i < 4; i++) {
        int b0 = b_base + w * 16 + quad * 4 + i;
        atomicAdd(&s_cur[(size_t)b0 * JD + jd0 + row],      acc0[i]);
        atomicAdd(&s_cur[(size_t)b0 * JD + jd0 + 16 + row], acc1[i]);
    }
}

// final: squash s2 -> out
__global__ __launch_bounds__(320) void k_rs_final(
    const float* __restrict__ s, float* __restrict__ out) {
    int t = threadIdx.x;                      // 320 = 2 b x 160 jd
    int bloc = t / JD, jd = t % JD;
    int b = blockIdx.x * 2 + bloc;
    float acc = s[(size_t)b * JD + jd];
    float sq = acc * acc;                     // lane%16 == jd%16 -> width-16 xor
#pragma unroll
    for (int off = 1; off < 16; off <<= 1) sq += __shfl_xor(sq, off, 16);
    float scale = sq / ((1.f + sq) * sqrtf(sq));
    out[(size_t)b * JD + jd] = acc * scale;
}

extern "C" void kernel_launch(void* const* d_in, const int* in_sizes, int n_in,
                              void* d_out, int out_size, void* d_ws, size_t ws_size,
                              hipStream_t stream) {
    const float* x = (const float*)d_in[0];   // [128,1152,8]
    const float* W = (const float*)d_in[1];   // [1,1152,10,16,8]
    float* out = (float*)d_out;               // [128,10,16,1]
    char* ws = (char*)d_ws;

    float*          b_ij   = (float*)(ws + 0);
    float*          s0     = (float*)(ws + 46080);
    float*          s1     = (float*)(ws + 46080 + 81920);
    float*          s2     = (float*)(ws + 46080 + 163840);
    unsigned int*   c1     = (unsigned int*)(ws + 291840);
    unsigned int*   c2     = (unsigned int*)(ws + 292032);
    float*          bupd_g = (float*)(ws + 292224);
    unsigned short* xT     = (unsigned short*)(ws + 338304);

    // zero b_ij + s0..s2 + c1/c2  (292224 B = 18264 float4)
    k_zero<<<72, 256, 0, stream>>>((float*)ws);

    // dispatch 1: iter1 (c=0.1, from x) + transpose x->xT, fused as 768 blocks
    k_first<<<768, 256, 0, stream>>>(x, W, xT, s0);

    // dispatch 2: va1 + iter2 (chunk-barrier fused) -> s1, b_ij updated
    k_fused<<<dim3(KSPLIT, NG, BH), 256, 0, stream>>>(
        x, xT, W, b_ij, s0, s1, bupd_g, c1);

    // dispatch 3: va2 + iter3 -> s2
    k_fused<<<dim3(KSPLIT, NG, BH), 256, 0, stream>>>(
        x, xT, W, b_ij, s1, s2, bupd_g, c2);

    // dispatch 4: final squash
    k_rs_final<<<64, 320, 0, stream>>>(s2, out);
}

// Round 4
// 111.619 us; speedup vs baseline: 1.5837x; 1.3259x over previous
//
#include <hip/hip_runtime.h>
#include <math.h>

#define R_ROUTES 1152
#define N_CAPS 10
#define C_IN 8
#define D_DIM 16
#define B_BATCH 128
#define JD 160                      // N_CAPS * D_DIM
#define KK 9216                     // R_ROUTES * C_IN (GEMM K)
#define KSPLIT 48                   // 24 routes = 192 k per split
#define RS 24                       // routes per k-split
#define NG 5                        // jd groups of 32
#define BH 2                        // batch halves
#define NBLK (KSPLIT * NG * BH)     // 480 blocks per iter grid

typedef __attribute__((ext_vector_type(8))) short short8;   // 8 bf16 (4 VGPRs)
typedef __attribute__((ext_vector_type(4))) float f32x4;    // MFMA accumulator

__device__ inline unsigned short f2bf(float f) {            // RNE fp32 -> bf16
    unsigned int u = __float_as_uint(f);
    unsigned int r = u + 0x7FFFu + ((u >> 16) & 1u);
    return (unsigned short)(r >> 16);
}
__device__ inline float bf2f(unsigned short h) {
    return __uint_as_float(((unsigned int)h) << 16);
}

// ---------------------------------------------------------------------------
// ws layout (byte offsets):
//   s0/s1/s2 fp32 [128][160]   @ 0        (3x81920, ends 245760)
//   b_ij fp32 [1152][10]       @ 245760   (46080; stored by va1, += by va2)
//   ctab fp32 [1152][10]       @ 291840   (46080; softmax(b) written by k_va)
//   xT   bf16 [9216][128]      @ 337920   (2359296; for M2 A-operand)
// Lesson log:
//  R7/R9 (112.4us, 7 dispatches): atomic split-K KSPLIT=48. R10/R11: atomic
//    throughput exonerated. R12: 2x waves NEUTRAL -> not occupancy-starved.
//  R13 REGRESSED (150us): per-block redundant full agreement = 55us/dispatch.
//  R14 REGRESSED (177us): serial single-block tail of agent-scope scalar
//    atomic loads = 15-25us x3. Tails must be parallel-wide + plain loads.
//  R15 REGRESSED (148us): 10-sibling chunk barrier (agent ACQ spin = cache
//    invalidate per poll, convoy) made fused kernel 42us vs ~30 unfused.
//  FIRM LESSON: in-kernel cross-block coordination costs >> 7us dispatch gap.
//    7 dispatches is the structural floor (s->v->b->c->s needs 2 syncs/iter).
//  R16 (this): keep 7 dispatches, shorten serial paths with verified pieces:
//    - k_iter: ZERO LDS, ZERO barriers. B-fragments built from global W in
//      regs (B[i] = f2bf(c[st*4+quad] * W[(r0+st*4+quad)*JD+jd][i]), 16-lane
//      coalesced 512B). softmax hoisted to k_va (ctab). A from x fp32 direct
//      (R15-verified hi/lo split).
//    - k_va: in-register W contract (R13/R15-verified), no m2 LDS, one less
//      barrier, LDS 65.8->43.6KB (3 blk/CU); computes softmax for its 4
//      routes -> ctab; va1 STORES b_ij (no zeroing), va2 accumulates.
//    - prep deleted: transpose + s1/s2-zero ride in the iter1 dispatch;
//      only s0-zero (82KB, 20 blocks) stays up front.
// ---------------------------------------------------------------------------

__global__ __launch_bounds__(256) void k_zero(f32x4* __restrict__ p) {
    int i = blockIdx.x * 256 + threadIdx.x;   // 20 blocks: 5120 f32x4 = s0
    p[i] = (f32x4){0.f, 0.f, 0.f, 0.f};
}

// Shared GEMM body: one routing iteration's weighted-sum GEMM.
// No LDS, no barriers: per step st, fragment route rl = st*4+quad;
// B built from W*c in regs, A from x fp32 hi/lo split. atomicAdd into s.
template <bool FIRST>
__device__ inline void iter_body(
    const float* __restrict__ x, const float* __restrict__ W,
    const float* __restrict__ ctab, float* __restrict__ s,
    int ks, int ng, int bh, int t) {
    int r0 = ks * RS, jd0 = ng * 32, b_base = bh * 64;
    int w = t >> 6, l = t & 63, row = l & 15, quad = l >> 4;
    const float* px = x + (size_t)(b_base + w * 16 + row) * KK + ks * 192;
    f32x4 acc0 = {0,0,0,0}, acc1 = {0,0,0,0};
#pragma unroll
    for (int st = 0; st < 6; st++) {          // K = 192 = 6 steps of 32
        int rr = r0 + st * 4 + quad;          // route of this fragment
        float c0 = FIRST ? 0.1f : ctab[rr * N_CAPS + (jd0 >> 4)];
        float c1 = FIRST ? 0.1f : ctab[rr * N_CAPS + (jd0 >> 4) + 1];
        const float4* wp0 = (const float4*)(W + ((size_t)rr * JD + jd0 + row) * C_IN);
        const float4* wp1 = (const float4*)(W + ((size_t)rr * JD + jd0 + 16 + row) * C_IN);
        float4 wa = wp0[0], wb = wp0[1], wc = wp1[0], wd = wp1[1];
        float wv0[8] = {wa.x,wa.y,wa.z,wa.w, wb.x,wb.y,wb.z,wb.w};
        float wv1[8] = {wc.x,wc.y,wc.z,wc.w, wd.x,wd.y,wd.z,wd.w};
        short8 Bh0, Bh1;
#pragma unroll
        for (int i = 0; i < 8; i++) {
            Bh0[i] = (short)f2bf(wv0[i] * c0);
            Bh1[i] = (short)f2bf(wv1[i] * c1);
        }
        float4 x0 = *(const float4*)(px + st * 32 + quad * 8);
        float4 x1 = *(const float4*)(px + st * 32 + quad * 8 + 4);
        float xv[8] = {x0.x,x0.y,x0.z,x0.w, x1.x,x1.y,x1.z,x1.w};
        short8 Ah, Al;
#pragma unroll
        for (int i = 0; i < 8; i++) {
            unsigned short h = f2bf(xv[i]);
            Ah[i] = (short)h;
            Al[i] = (short)f2bf(xv[i] - bf2f(h));
        }
        acc0 = __builtin_amdgcn_mfma_f32_16x16x32_bf16(Ah, Bh0, acc0, 0, 0, 0);
        acc0 = __builtin_amdgcn_mfma_f32_16x16x32_bf16(Al, Bh0, acc0, 0, 0, 0);
        acc1 = __builtin_amdgcn_mfma_f32_16x16x32_bf16(Ah, Bh1, acc1, 0, 0, 0);
        acc1 = __builtin_amdgcn_mfma_f32_16x16x32_bf16(Al, Bh1, acc1, 0, 0, 0);
    }
#pragma unroll
    for (int i = 0; i < 4; i++) {             // C/D: col=lane&15 (jd), row=quad*4+i (b)
        int b0 = b_base + w * 16 + quad * 4 + i;
        atomicAdd(&s[(size_t)b0 * JD + jd0 + row],      acc0[i]);
        atomicAdd(&s[(size_t)b0 * JD + jd0 + 16 + row], acc1[i]);
    }
}

// Dispatch 2: blocks 0..479 iter1 (c=0.1); 480..767 transpose x->xT;
//             768..807 zero s1/s2 (not read until dispatch 4/6).
__global__ __launch_bounds__(256) void k_first(
    const float* __restrict__ x, const float* __restrict__ W,
    unsigned short* __restrict__ xT, float* __restrict__ s0,
    f32x4* __restrict__ z12) {
    __shared__ float tile[32][33];
    int id = blockIdx.x, t = threadIdx.x;

    if (id < NBLK) {                          // ---- iter1 role ----
        iter_body<true>(x, W, nullptr, s0, id % KSPLIT, (id / KSPLIT) % NG,
                        id / (KSPLIT * NG), t);
        return;
    }
    if (id < NBLK + 288) {                    // ---- transpose role ----
        int bx = id - NBLK;                   // rc tile 0..287
        int tx = t & 31, ty = t >> 5;
        for (int by = 0; by < 4; by++) {
            if (by) __syncthreads();
#pragma unroll
            for (int i = 0; i < 4; i++) {
                int row = ty + i * 8;         // b_local
                tile[row][tx] = x[(size_t)(by * 32 + row) * KK + bx * 32 + tx];
            }
            __syncthreads();
#pragma unroll
            for (int i = 0; i < 4; i++) {
                int row = ty + i * 8;         // rc_local
                xT[(size_t)(bx * 32 + row) * B_BATCH + by * 32 + tx] = f2bf(tile[tx][row]);
            }
        }
        return;
    }
    // ---- zero role: s1+s2 = 10240 f32x4 over 40 blocks ----
    int idx = (id - (NBLK + 288)) * 256 + t;
    z12[idx] = (f32x4){0.f, 0.f, 0.f, 0.f};
}

// Standalone iteration GEMM (iter2/iter3), grid (48,5,2).
__global__ __launch_bounds__(256) void k_iter(
    const float* __restrict__ x, const float* __restrict__ W,
    const float* __restrict__ ctab, float* __restrict__ s) {
    iter_body<false>(x, W, ctab, s, blockIdx.x, blockIdx.y, blockIdx.z,
                     threadIdx.x);
}

// Agreement + softmax: squash(s_prev)->vb, M2 via MFMA with in-register W
// contract (no m2 LDS), b_new for this block's 4 routes, softmax -> ctab.
// ACCUM=0 (va1): b_ij = upd (store; no zeroing needed).
// ACCUM=1 (va2): b_ij + upd (no store back; last use).
template <int ACCUM>
__global__ __launch_bounds__(256) void k_va(
    const unsigned short* __restrict__ xT, const float* __restrict__ s_prev,
    const float* __restrict__ W, float* __restrict__ b_ij,
    float* __restrict__ ctab) {
    __shared__ unsigned short vb[JD][136];    // [jd][b], +8 pad (43520 B)
    __shared__ float bnew[4][N_CAPS];
    int t = threadIdx.x;
    int r0 = blockIdx.x * 4, rc0 = blockIdx.x * 32;

    // --- squash(s_prev) -> vb (verified R15 float4 version) -------------
#pragma unroll
    for (int q = 0; q < 5; q++) {
        int pi = t * 5 + q;                   // (b, j) pair, 1280 total
        int b = pi / N_CAPS, j = pi % N_CAPS;
        const float4* sp4 = (const float4*)(s_prev + (size_t)b * JD + j * D_DIM);
        float4 a0 = sp4[0], a1 = sp4[1], a2 = sp4[2], a3 = sp4[3];
        float sv[D_DIM] = {a0.x,a0.y,a0.z,a0.w, a1.x,a1.y,a1.z,a1.w,
                           a2.x,a2.y,a2.z,a2.w, a3.x,a3.y,a3.z,a3.w};
        float sqn = 0.f;
#pragma unroll
        for (int d = 0; d < D_DIM; d++) sqn = fmaf(sv[d], sv[d], sqn);
        float scale = sqn / ((1.f + sqn) * sqrtf(sqn));
#pragma unroll
        for (int d = 0; d < D_DIM; d++)
            vb[j * D_DIM + d][b] = f2bf(sv[d] * scale);
    }
    __syncthreads();

    int w = t >> 6, l = t & 63, row = l & 15, quad = l >> 4;
    int rhalf = l >> 5, cbase = (quad & 1) * 4;

    // --- M2 tiles + in-register W contract (verified R13/R15) -----------
    // tile (mt,nt): acc[i] = M2[rc=mt*16+quad*4+i][jd=nt*16+row];
    // route = r0+2mt+rhalf, c = cbase+i; reduce over 32-lane half.
    for (int u = w; u < 20; u += 4) {         // 5 tiles/wave
        int mt = u / 10, nt = u % 10;
        const short8* pa = (const short8*)(xT + (size_t)(rc0 + mt * 16 + row) * B_BATCH);
        f32x4 acc = {0,0,0,0};
#pragma unroll
        for (int st = 0; st < 4; st++)        // K = 128 = 4 steps of 32
            acc = __builtin_amdgcn_mfma_f32_16x16x32_bf16(
                pa[st * 4 + quad],
                *(const short8*)&vb[nt * 16 + row][st * 32 + quad * 8],
                acc, 0, 0, 0);
        int r = r0 + 2 * mt + rhalf;
        const float* wp = W + ((size_t)r * JD + nt * 16 + row) * C_IN + cbase;
        float4 w4 = *(const float4*)wp;
        float part = acc[0]*w4.x + acc[1]*w4.y + acc[2]*w4.z + acc[3]*w4.w;
#pragma unroll
        for (int off = 1; off < 32; off <<= 1) part += __shfl_xor(part, off, 32);
        if ((l & 31) == 0) bnew[2 * mt + rhalf][nt] = part * (1.f / (float)B_BATCH);
    }
    __syncthreads();

    // --- softmax for this block's 4 routes -> ctab (and b_ij chain) ------
    if (t < 4) {
        float bj[N_CAPS], m = -1e30f;
#pragma unroll
        for (int j = 0; j < N_CAPS; j++) {
            float base = ACCUM ? b_ij[(r0 + t) * N_CAPS + j] : 0.f;
            bj[j] = base + bnew[t][j];
            m = fmaxf(m, bj[j]);
        }
        if (!ACCUM) {
#pragma unroll
            for (int j = 0; j < N_CAPS; j++) b_ij[(r0 + t) * N_CAPS + j] = bj[j];
        }
        float sum = 0.f;
#pragma unroll
        for (int j = 0; j < N_CAPS; j++) { bj[j] = expf(bj[j] - m); sum += bj[j]; }
        float inv = 1.f / sum;
#pragma unroll
        for (int j = 0; j < N_CAPS; j++) ctab[(r0 + t) * N_CAPS + j] = bj[j] * inv;
    }
}

// final: squash s2 -> out
__global__ __launch_bounds__(320) void k_rs_final(
    const float* __restrict__ s, float* __restrict__ out) {
    int t = threadIdx.x;                      // 320 = 2 b x 160 jd
    int bloc = t / JD, jd = t % JD;
    int b = blockIdx.x * 2 + bloc;
    float acc = s[(size_t)b * JD + jd];
    float sq = acc * acc;                     // lane%16 == jd%16 -> width-16 xor
#pragma unroll
    for (int off = 1; off < 16; off <<= 1) sq += __shfl_xor(sq, off, 16);
    float scale = sq / ((1.f + sq) * sqrtf(sq));
    out[(size_t)b * JD + jd] = acc * scale;
}

extern "C" void kernel_launch(void* const* d_in, const int* in_sizes, int n_in,
                              void* d_out, int out_size, void* d_ws, size_t ws_size,
                              hipStream_t stream) {
    const float* x = (const float*)d_in[0];   // [128,1152,8]
    const float* W = (const float*)d_in[1];   // [1,1152,10,16,8]
    float* out = (float*)d_out;               // [128,10,16,1]
    char* ws = (char*)d_ws;

    float*          s0   = (float*)(ws + 0);
    float*          s1   = (float*)(ws + 81920);
    float*          s2   = (float*)(ws + 163840);
    float*          b_ij = (float*)(ws + 245760);
    float*          ctab = (float*)(ws + 291840);
    unsigned short* xT   = (unsigned short*)(ws + 337920);

    // d1: zero s0 (82KB)
    k_zero<<<20, 256, 0, stream>>>((f32x4*)s0);

    // d2: iter1 (c=0.1) + transpose x->xT + zero s1/s2
    k_first<<<808, 256, 0, stream>>>(x, W, xT, s0, (f32x4*)s1);

    // d3: va1 -> b_ij (store), ctab
    k_va<0><<<288, 256, 0, stream>>>(xT, s0, W, b_ij, ctab);

    // d4: iter2 -> s1
    k_iter<<<dim3(KSPLIT, NG, BH), 256, 0, stream>>>(x, W, ctab, s1);

    // d5: va2 -> ctab (b_ij + upd2)
    k_va<1><<<288, 256, 0, stream>>>(xT, s1, W, b_ij, ctab);

    // d6: iter3 -> s2
    k_iter<<<dim3(KSPLIT, NG, BH), 256, 0, stream>>>(x, W, ctab, s2);

    // d7: final squash
    k_rs_final<<<64, 320, 0, stream>>>(s2, out);
}